// Round 1
// baseline (232.428 us; speedup 1.0000x reference)
//
#include <hip/hip_runtime.h>

typedef float v2f __attribute__((ext_vector_type(2)));
typedef float v4f __attribute__((ext_vector_type(4)));

#define DD   187   // input dim
#define HH   50    // hidden
#define PH   64    // padded hidden (8 lanes x 8)
#define HPJ  8     // hidden neurons per lane
#define NP   4     // float2 pairs per lane
#define NC   5     // classes
#define RPB  32    // rows per block (8 lanes/row, 256 threads)
#define BLK  256
#define DCH  64    // d-chunk
#define NCHUNK 3   // ceil(187/64)
#define XSS  68    // xs row stride (mult of 4 -> 16B aligned float4 reads, banks spread)
#define BETA 0.9f

__device__ __forceinline__ float dpp_xor1(float v) {
    // quad_perm [1,0,3,2] -> lane^1
    return __builtin_bit_cast(float,
        __builtin_amdgcn_mov_dpp(__builtin_bit_cast(int, v), 0xB1, 0xF, 0xF, true));
}
__device__ __forceinline__ float dpp_xor2(float v) {
    // quad_perm [2,3,0,1] -> lane^2
    return __builtin_bit_cast(float,
        __builtin_amdgcn_mov_dpp(__builtin_bit_cast(int, v), 0x4E, 0xF, 0xF, true));
}
__device__ __forceinline__ float dpp_xor8(float v) {
    // row_ror:8 -> within each 16-lane row, lane l reads lane (l+8)%16 == l^8
    return __builtin_bit_cast(float,
        __builtin_amdgcn_mov_dpp(__builtin_bit_cast(int, v), 0x128, 0xF, 0xF, true));
}

__device__ __forceinline__ float spike1(float m) {
    // exact (m > 1) ? 1 : 0 : fma(m,2^60,-2^60) > 0 iff m>1 (f32), clamp to [0,1]
    float t = fmaf(m, 0x1.0p60f, -0x1.0p60f);
    return fminf(fmaxf(t, 0.f), 1.f);
}
__device__ __forceinline__ v2f spike2(v2f m) {
    const v2f BIG2  = { 0x1.0p60f,  0x1.0p60f};
    const v2f NBIG2 = {-0x1.0p60f, -0x1.0p60f};
    const v2f ONE2  = {1.f, 1.f};
    const v2f ZERO2 = {0.f, 0.f};
    v2f t = __builtin_elementwise_fma(m, BIG2, NBIG2);
    return __builtin_elementwise_min(__builtin_elementwise_max(t, ZERO2), ONE2);
}

__global__ __launch_bounds__(BLK, 4)
void snn_kernel(const float* __restrict__ x,
                const float* __restrict__ W1,
                const float* __restrict__ b1,
                const float* __restrict__ W2,
                const float* __restrict__ b2,
                const int*   __restrict__ nsp,
                float* __restrict__ out, int Brows)
{
    __shared__ float xs[RPB * XSS];   //  8,704 B
    __shared__ float w1t[DCH * PH];   // 16,384 B (d-major, h padded to 64)

    const int tid = threadIdx.x;
    const int l   = tid & 15;                    // lane within 16-row
    const int g   = tid >> 4;                    // 16-lane group id within block
    // row lanes form the xor-closure of {1,2,8}: {0,1,2,3,8,9,10,11} (+4 for 2nd row)
    const int hb  = (l >> 2) & 1;                // which row of the pair
    const int p   = g * 2 + hb;                  // row within block 0..31
    const int k   = (l & 3) | ((l & 8) >> 1);    // hidden-slice 0..7
    const int row = blockIdx.x * RPB + p;
    const int NS  = nsp[0];

    // ---------------- Phase 1: cur1 = x @ W1^T (chunked over d) ----------------
    v2f acc[NP];
#pragma unroll
    for (int i = 0; i < NP; ++i) acc[i] = (v2f){0.f, 0.f};

    for (int ch = 0; ch < NCHUNK; ++ch) {
        const int d0 = ch * DCH;
        for (int i = tid; i < RPB * DCH; i += BLK) {
            int r = i >> 6, dd = i & 63;
            int d = d0 + dd;
            xs[r * XSS + dd] = (d < DD) ? x[(size_t)(blockIdx.x * RPB + r) * DD + d] : 0.f;
        }
        // conflict-free staging: per wave h runs 0..63 (consecutive LDS addresses)
        for (int i = tid; i < DCH * PH; i += BLK) {
            int dd = i >> 6, h = i & 63;
            int d = d0 + dd;
            w1t[dd * PH + h] = (h < HH && d < DD) ? W1[h * DD + d] : 0.f;
        }
        __syncthreads();

        const float* xr = xs + p * XSS;
#pragma unroll 4
        for (int d4 = 0; d4 < DCH / 4; ++d4) {
            v4f xv4 = *(const v4f*)(xr + 4 * d4);
#pragma unroll
            for (int j = 0; j < 4; ++j) {
                int d = 4 * d4 + j;
                const v4f* wr = (const v4f*)(w1t + d * PH + k * HPJ); // 16B aligned
                v4f wa = wr[0], wb = wr[1];
                float xv = xv4[j];
                v2f xvv = {xv, xv};
                acc[0] = __builtin_elementwise_fma(xvv, __builtin_shufflevector(wa, wa, 0, 1), acc[0]);
                acc[1] = __builtin_elementwise_fma(xvv, __builtin_shufflevector(wa, wa, 2, 3), acc[1]);
                acc[2] = __builtin_elementwise_fma(xvv, __builtin_shufflevector(wb, wb, 0, 1), acc[2]);
                acc[3] = __builtin_elementwise_fma(xvv, __builtin_shufflevector(wb, wb, 2, 3), acc[3]);
            }
        }
        __syncthreads();
    }

    // cur1 = acc + b1 (pads stay 0 -> padded neurons never spike)
    v2f c1[NP];
#pragma unroll
    for (int i = 0; i < NP; ++i) {
        int h0 = k * HPJ + 2 * i;
        v2f bb;
        bb.x = (h0     < HH) ? b1[h0]     : 0.f;
        bb.y = (h0 + 1 < HH) ? b1[h0 + 1] : 0.f;
        c1[i] = acc[i] + bb;
    }
    // bias neuron: pad slot h=63 fires every step (m: 2 -> ... -> 10, always > 1),
    // its W2 column is b2 -> cur2 sum arrives with bias already included.
    if (k == 7) c1[3].y = 2.0f;

    // W2 fragments (40 VGPRs)
    v2f w2r[NC][NP];
#pragma unroll
    for (int c = 0; c < NC; ++c)
#pragma unroll
        for (int i = 0; i < NP; ++i) {
            int h0 = k * HPJ + 2 * i;
            w2r[c][i].x = (h0     < HH) ? W2[c * HH + h0]     : 0.f;
            w2r[c][i].y = (h0 + 1 < HH) ? W2[c * HH + h0 + 1] : 0.f;
        }
    if (k == 7) {
#pragma unroll
        for (int c = 0; c < NC; ++c) w2r[c][3].y = b2[c];
    }

    // ---------------- Phase 2: 100-step LIF recurrence ----------------
    v2f m1[NP], s1[NP];
#pragma unroll
    for (int i = 0; i < NP; ++i) { m1[i] = (v2f){0.f, 0.f}; s1[i] = (v2f){0.f, 0.f}; }
    float mA = 0.f, sA = 0.f;

    const size_t stride = (size_t)Brows * NC;
    float* spkBase = out;                          // + t*stride each step (wave-uniform)
    float* memBase = out + (size_t)NS * stride;
    const int offA = row * NC + k;                 // owner lanes cover 5 consecutive dwords
    const bool owner = (k < NC);                   // lane k owns class k
    const v2f BETA2 = {BETA, BETA};

    for (int t = 0; t < NS; ++t) {
        v2f cp[NC];
#pragma unroll
        for (int c = 0; c < NC; ++c) cp[c] = (v2f){0.f, 0.f};
#pragma unroll
        for (int i = 0; i < NP; ++i) {
            // mem1 = beta*mem1 + cur1 - reset1 (reset1 == previous spike)
            v2f m = __builtin_elementwise_fma(BETA2, m1[i], c1[i]) - s1[i];
            m1[i] = m;
            v2f s = spike2(m);
            s1[i] = s;
#pragma unroll
            for (int c = 0; c < NC; ++c)
                cp[c] = __builtin_elementwise_fma(s, w2r[c][i], cp[c]);
        }
        // horizontal + 3-stage all-DPP butterfly over the row's 8 lanes
        float cur2[NC];
#pragma unroll
        for (int c = 0; c < NC; ++c) {
            float r = cp[c].x + cp[c].y;
            r += dpp_xor1(r);
            r += dpp_xor2(r);
            r += dpp_xor8(r);
            cur2[c] = r;
        }
        float cA = (k == 1) ? cur2[1] : (k == 2) ? cur2[2] :
                   (k == 3) ? cur2[3] : (k == 4) ? cur2[4] : cur2[0];

        mA = fmaf(BETA, mA, cA) - sA;   // b2 folded into cA via bias neuron
        sA = spike1(mA);

        if (owner) {
            spkBase[offA] = sA;
            memBase[offA] = mA;
        }
        spkBase += stride;
        memBase += stride;
    }
}

extern "C" void kernel_launch(void* const* d_in, const int* in_sizes, int n_in,
                              void* d_out, int out_size, void* d_ws, size_t ws_size,
                              hipStream_t stream) {
    const float* x  = (const float*)d_in[0];
    const float* W1 = (const float*)d_in[1];
    const float* b1 = (const float*)d_in[2];
    const float* W2 = (const float*)d_in[3];
    const float* b2 = (const float*)d_in[4];
    const int*   ns = (const int*)d_in[5];
    int B = in_sizes[0] / DD;          // 32768
    int nblocks = B / RPB;             // 1024 -> 4 blocks/CU, 16 waves/CU
    snn_kernel<<<nblocks, BLK, 0, stream>>>(x, W1, b1, W2, b2, ns, (float*)d_out, B);
}

// Round 2
// 223.181 us; speedup vs baseline: 1.0414x; 1.0414x over previous
//
#include <hip/hip_runtime.h>

typedef float v2f __attribute__((ext_vector_type(2)));
typedef float v4f __attribute__((ext_vector_type(4)));

#define DD   187   // input dim
#define HH   50    // hidden
#define PH   64    // LDS padded hidden (4 lanes x 16 slots)
#define HPJ  14    // hidden neurons per lane (logical)
#define HPL  16    // LDS slots per lane (64B -> b128-aligned reads)
#define NP   7     // float2 pairs per lane
#define NC   5     // classes
#define RPB  64    // rows per block (4 lanes/row, 256 threads)
#define BLK  256
#define DCH  64    // d-chunk
#define NCHUNK 3   // ceil(187/64)
#define XSS  68    // xs row stride (mult of 4 -> 16B-aligned v4f reads)
#define BETA 0.9f

__device__ __forceinline__ float dpp_xor1(float v) {
    // quad_perm [1,0,3,2] -> lane^1
    return __builtin_bit_cast(float,
        __builtin_amdgcn_mov_dpp(__builtin_bit_cast(int, v), 0xB1, 0xF, 0xF, true));
}
__device__ __forceinline__ float dpp_xor2(float v) {
    // quad_perm [2,3,0,1] -> lane^2
    return __builtin_bit_cast(float,
        __builtin_amdgcn_mov_dpp(__builtin_bit_cast(int, v), 0x4E, 0xF, 0xF, true));
}

__device__ __forceinline__ float spike1(float m) {
    // exact (m > 1) ? 1 : 0 : fma(m,2^60,-2^60) > 0 iff m>1 (f32), clamp to [0,1]
    float t = fmaf(m, 0x1.0p60f, -0x1.0p60f);
    return fminf(fmaxf(t, 0.f), 1.f);
}
__device__ __forceinline__ v2f spike2(v2f m) {
    const v2f BIG2  = { 0x1.0p60f,  0x1.0p60f};
    const v2f NBIG2 = {-0x1.0p60f, -0x1.0p60f};
    const v2f ONE2  = {1.f, 1.f};
    const v2f ZERO2 = {0.f, 0.f};
    v2f t = __builtin_elementwise_fma(m, BIG2, NBIG2);
    return __builtin_elementwise_min(__builtin_elementwise_max(t, ZERO2), ONE2);
}

__device__ __forceinline__ v2f vlo(v4f v) { return __builtin_shufflevector(v, v, 0, 1); }
__device__ __forceinline__ v2f vhi(v4f v) { return __builtin_shufflevector(v, v, 2, 3); }

// waves_per_eu(2,2): grid is structurally 2 waves/SIMD (2048 waves / 1024 SIMDs);
// pin the allocator's occupancy target so w2r/c1/m1/s1 stay resident in arch VGPRs
// instead of being squeezed into AGPR-shuffles / per-step reloads (round-0/1 showed
// VGPR_Count 72/56 < live set -> weights were NOT register-resident).
__global__ __launch_bounds__(BLK) __attribute__((amdgpu_waves_per_eu(2, 2)))
void snn_kernel(const float* __restrict__ x,
                const float* __restrict__ W1,
                const float* __restrict__ b1,
                const float* __restrict__ W2,
                const float* __restrict__ b2,
                const int*   __restrict__ nsp,
                float* __restrict__ out, int Brows)
{
    __shared__ __align__(16) float xs[RPB * XSS];   // 17,408 B
    __shared__ __align__(16) float w1t[DCH * PH];   // 16,384 B (d-major, 4x16 slots)

    const int tid = threadIdx.x;
    const int p   = tid >> 2;         // row within block (quad id)
    const int k   = tid & 3;          // lane within quad: hidden slice + class owner
    const int row = blockIdx.x * RPB + p;
    const int NS  = nsp[0];

    // ---------------- Phase 1: cur1 = x @ W1^T (chunked over d) ----------------
    v2f acc[NP];
#pragma unroll
    for (int i = 0; i < NP; ++i) acc[i] = (v2f){0.f, 0.f};

    for (int ch = 0; ch < NCHUNK; ++ch) {
        const int d0 = ch * DCH;
        for (int i = tid; i < RPB * DCH; i += BLK) {
            int r = i >> 6, dd = i & 63;
            int d = d0 + dd;
            xs[r * XSS + dd] = (d < DD) ? x[(size_t)(blockIdx.x * RPB + r) * DD + d] : 0.f;
        }
        // conflict-free staging: consecutive threads -> consecutive LDS addresses.
        // slot s = kk*16 + j holds logical hidden h = kk*14 + j (j<14), pads zero.
        for (int i = tid; i < DCH * PH; i += BLK) {
            int dd = i >> 6, s = i & 63;
            int kk = s >> 4, j = s & 15;
            int h = kk * HPJ + j;
            int d = d0 + dd;
            w1t[dd * PH + s] = (j < HPJ && h < HH && d < DD) ? W1[h * DD + d] : 0.f;
        }
        __syncthreads();

        const float* xr = xs + p * XSS;
#pragma unroll 2
        for (int d4 = 0; d4 < DCH / 4; ++d4) {
            v4f xv4 = *(const v4f*)(xr + 4 * d4);
#pragma unroll
            for (int j = 0; j < 4; ++j) {
                int d = 4 * d4 + j;
                const float* wbase = w1t + d * PH + k * HPL;   // 64B aligned per lane
                v4f w0 = *(const v4f*)(wbase);
                v4f w1v = *(const v4f*)(wbase + 4);
                v4f w2v = *(const v4f*)(wbase + 8);
                v2f w3 = *(const v2f*)(wbase + 12);            // pairs (12,13)
                float xv = xv4[j];
                v2f xvv = {xv, xv};
                acc[0] = __builtin_elementwise_fma(xvv, vlo(w0),  acc[0]);
                acc[1] = __builtin_elementwise_fma(xvv, vhi(w0),  acc[1]);
                acc[2] = __builtin_elementwise_fma(xvv, vlo(w1v), acc[2]);
                acc[3] = __builtin_elementwise_fma(xvv, vhi(w1v), acc[3]);
                acc[4] = __builtin_elementwise_fma(xvv, vlo(w2v), acc[4]);
                acc[5] = __builtin_elementwise_fma(xvv, vhi(w2v), acc[5]);
                acc[6] = __builtin_elementwise_fma(xvv, w3,       acc[6]);
            }
        }
        __syncthreads();
    }

    // cur1 = acc + b1 (pads stay 0 -> padded neurons never spike)
    v2f c1[NP];
#pragma unroll
    for (int i = 0; i < NP; ++i) {
        int h0 = k * HPJ + 2 * i;
        v2f bb;
        bb.x = (h0     < HH) ? b1[h0]     : 0.f;
        bb.y = (h0 + 1 < HH) ? b1[h0 + 1] : 0.f;
        c1[i] = acc[i] + bb;
    }
    // bias neuron: pad slot h=55 (k=3, pair 6, .y) fires every step (m: 2 -> 10, >1),
    // its W2 column is b2 -> cur2 arrives with bias already included (all 5 classes).
    if (k == 3) c1[6].y = 2.0f;

    // W2 fragments (70 VGPRs) — resident thanks to waves_per_eu(2,2)
    v2f w2r[NC][NP];
#pragma unroll
    for (int c = 0; c < NC; ++c)
#pragma unroll
        for (int i = 0; i < NP; ++i) {
            int h0 = k * HPJ + 2 * i;
            w2r[c][i].x = (h0     < HH) ? W2[c * HH + h0]     : 0.f;
            w2r[c][i].y = (h0 + 1 < HH) ? W2[c * HH + h0 + 1] : 0.f;
        }
    if (k == 3) {
#pragma unroll
        for (int c = 0; c < NC; ++c) w2r[c][6].y = b2[c];
    }

    // ---------------- Phase 2: 100-step LIF recurrence (software-pipelined) -----
    v2f m1[NP], s1[NP];
#pragma unroll
    for (int i = 0; i < NP; ++i) { m1[i] = (v2f){0.f, 0.f}; s1[i] = (v2f){0.f, 0.f}; }
    float mA = 0.f, sA = 0.f, mB = 0.f, sB = 0.f;

    const size_t stride = (size_t)Brows * NC;
    float* spkBase = out;                          // + t*stride each step (wave-uniform)
    float* memBase = out + (size_t)NS * stride;
    const int offA = row * NC + k;                 // lanes k=0..3 -> 4 consecutive dwords
    const int offB = row * NC + 4;
    const v2f BETA2 = {BETA, BETA};

    v2f cp[NC];
    // layer-1 step: advance m1/s1 one step and produce fresh class partials cp
    auto S1 = [&]() {
#pragma unroll
        for (int c = 0; c < NC; ++c) cp[c] = (v2f){0.f, 0.f};
#pragma unroll
        for (int i = 0; i < NP; ++i) {
            v2f m = __builtin_elementwise_fma(BETA2, m1[i], c1[i]) - s1[i];
            m1[i] = m;
            v2f s = spike2(m);
            s1[i] = s;
#pragma unroll
            for (int c = 0; c < NC; ++c)
                cp[c] = __builtin_elementwise_fma(s, w2r[c][i], cp[c]);
        }
    };

    S1();   // cp for t = 0
    for (int t = 0; t < NS; ++t) {
        // quad butterfly reduction of step t's partials
        float cur2[NC];
#pragma unroll
        for (int c = 0; c < NC; ++c) {
            float r = cp[c].x + cp[c].y;
            r += dpp_xor1(r);
            r += dpp_xor2(r);
            cur2[c] = r;
        }
        // layer-1 of step t+1 — independent of cur2; scheduler interleaves these
        // ~100 ops into the DPP wait-states and the serial layer-2 chain below.
        // (extra run at t = NS-1 touches no memory; harmless)
        S1();

        float cA = (k == 1) ? cur2[1] : (k == 2) ? cur2[2] :
                   (k == 3) ? cur2[3] : cur2[0];
        float cB = cur2[4];

        mA = fmaf(BETA, mA, cA) - sA;   // b2 folded in via bias neuron
        sA = spike1(mA);
        mB = fmaf(BETA, mB, cB) - sB;
        sB = spike1(mB);

        spkBase[offA] = sA;                   // 4 consecutive dwords per quad
        memBase[offA] = mA;
        if (k == 0) { spkBase[offB] = sB; memBase[offB] = mB; }

        spkBase += stride;
        memBase += stride;
    }
}

extern "C" void kernel_launch(void* const* d_in, const int* in_sizes, int n_in,
                              void* d_out, int out_size, void* d_ws, size_t ws_size,
                              hipStream_t stream) {
    const float* x  = (const float*)d_in[0];
    const float* W1 = (const float*)d_in[1];
    const float* b1 = (const float*)d_in[2];
    const float* W2 = (const float*)d_in[3];
    const float* b2 = (const float*)d_in[4];
    const int*   ns = (const int*)d_in[5];
    int B = in_sizes[0] / DD;          // 32768
    int nblocks = B / RPB;             // 512 -> 2 blocks/CU, 8 waves/CU
    snn_kernel<<<nblocks, BLK, 0, stream>>>(x, W1, b1, W2, b2, ns, (float*)d_out, B);
}

// Round 3
// 219.860 us; speedup vs baseline: 1.0572x; 1.0151x over previous
//
#include <hip/hip_runtime.h>

typedef float v2f __attribute__((ext_vector_type(2)));
typedef float v4f __attribute__((ext_vector_type(4)));

#define DD   187   // input dim
#define HH   50    // hidden
#define PH   64    // LDS padded hidden (4 lanes x 16 slots)
#define HPJ  14    // hidden neurons per lane (logical)
#define HPL  16    // LDS slots per lane (64B -> b128-aligned reads)
#define NP   7     // float2 pairs per lane
#define NC   5     // classes
#define RPB  64    // rows per block (4 lanes/row, 256 threads)
#define BLK  256
#define DCH  64    // d-chunk
#define NCHUNK 3   // ceil(187/64)
#define XSS  68    // xs row stride (mult of 4 -> 16B-aligned v4f reads)
#define BETA 0.9f

__device__ __forceinline__ float dpp_xor1(float v) {
    // quad_perm [1,0,3,2] -> lane^1
    return __builtin_bit_cast(float,
        __builtin_amdgcn_mov_dpp(__builtin_bit_cast(int, v), 0xB1, 0xF, 0xF, true));
}
__device__ __forceinline__ float dpp_xor2(float v) {
    // quad_perm [2,3,0,1] -> lane^2
    return __builtin_bit_cast(float,
        __builtin_amdgcn_mov_dpp(__builtin_bit_cast(int, v), 0x4E, 0xF, 0xF, true));
}

__device__ __forceinline__ float spike1(float m) {
    // exact (m > 1) ? 1 : 0 : fma(m,2^60,-2^60) > 0 iff m>1 (f32), clamp to [0,1]
    float t = fmaf(m, 0x1.0p60f, -0x1.0p60f);
    return fminf(fmaxf(t, 0.f), 1.f);
}
__device__ __forceinline__ v2f spike2(v2f m) {
    const v2f BIG2  = { 0x1.0p60f,  0x1.0p60f};
    const v2f NBIG2 = {-0x1.0p60f, -0x1.0p60f};
    const v2f ONE2  = {1.f, 1.f};
    const v2f ZERO2 = {0.f, 0.f};
    v2f t = __builtin_elementwise_fma(m, BIG2, NBIG2);
    return __builtin_elementwise_min(__builtin_elementwise_max(t, ZERO2), ONE2);
}

__device__ __forceinline__ v2f vlo(v4f v) { return __builtin_shufflevector(v, v, 0, 1); }
__device__ __forceinline__ v2f vhi(v4f v) { return __builtin_shufflevector(v, v, 2, 3); }

// Structural occupancy is 2 waves/SIMD (2048 waves / 1024 SIMDs) -> register budget
// is 256/wave. launch_bounds 2nd arg = min waves per EU (NOT workgroups/CU).
__global__ __launch_bounds__(BLK, 2) __attribute__((amdgpu_waves_per_eu(2, 2)))
void snn_kernel(const float* __restrict__ x,
                const float* __restrict__ W1,
                const float* __restrict__ b1,
                const float* __restrict__ W2,
                const float* __restrict__ b2,
                const int*   __restrict__ nsp,
                float* __restrict__ out, int Brows)
{
    __shared__ __align__(16) float xs[RPB * XSS];   // 17,408 B
    __shared__ __align__(16) float w1t[DCH * PH];   // 16,384 B (d-major, 4x16 slots)

    const int tid = threadIdx.x;
    const int p   = tid >> 2;         // row within block (quad id)
    const int k   = tid & 3;          // lane within quad: hidden slice + class owner
    const int row = blockIdx.x * RPB + p;
    const int NS  = nsp[0];

    // ---------------- Phase 1: cur1 = x @ W1^T (chunked over d) ----------------
    v2f acc[NP];
#pragma unroll
    for (int i = 0; i < NP; ++i) acc[i] = (v2f){0.f, 0.f};

    for (int ch = 0; ch < NCHUNK; ++ch) {
        const int d0 = ch * DCH;
        for (int i = tid; i < RPB * DCH; i += BLK) {
            int r = i >> 6, dd = i & 63;
            int d = d0 + dd;
            xs[r * XSS + dd] = (d < DD) ? x[(size_t)(blockIdx.x * RPB + r) * DD + d] : 0.f;
        }
        // conflict-free staging: consecutive threads -> consecutive LDS addresses.
        // slot s = kk*16 + j holds logical hidden h = kk*14 + j (j<14), pads zero.
        for (int i = tid; i < DCH * PH; i += BLK) {
            int dd = i >> 6, s = i & 63;
            int kk = s >> 4, j = s & 15;
            int h = kk * HPJ + j;
            int d = d0 + dd;
            w1t[dd * PH + s] = (j < HPJ && h < HH && d < DD) ? W1[h * DD + d] : 0.f;
        }
        __syncthreads();

        const float* xr = xs + p * XSS;
#pragma unroll 2
        for (int d4 = 0; d4 < DCH / 4; ++d4) {
            v4f xv4 = *(const v4f*)(xr + 4 * d4);
#pragma unroll
            for (int j = 0; j < 4; ++j) {
                int d = 4 * d4 + j;
                const float* wbase = w1t + d * PH + k * HPL;   // 64B aligned per lane
                v4f w0 = *(const v4f*)(wbase);
                v4f w1v = *(const v4f*)(wbase + 4);
                v4f w2v = *(const v4f*)(wbase + 8);
                v2f w3 = *(const v2f*)(wbase + 12);            // pairs (12,13)
                float xv = xv4[j];
                v2f xvv = {xv, xv};
                acc[0] = __builtin_elementwise_fma(xvv, vlo(w0),  acc[0]);
                acc[1] = __builtin_elementwise_fma(xvv, vhi(w0),  acc[1]);
                acc[2] = __builtin_elementwise_fma(xvv, vlo(w1v), acc[2]);
                acc[3] = __builtin_elementwise_fma(xvv, vhi(w1v), acc[3]);
                acc[4] = __builtin_elementwise_fma(xvv, vlo(w2v), acc[4]);
                acc[5] = __builtin_elementwise_fma(xvv, vhi(w2v), acc[5]);
                acc[6] = __builtin_elementwise_fma(xvv, w3,       acc[6]);
            }
        }
        __syncthreads();
    }

    // cur1 = acc + b1 (pads stay 0 -> padded neurons never spike)
    v2f c1[NP];
#pragma unroll
    for (int i = 0; i < NP; ++i) {
        int h0 = k * HPJ + 2 * i;
        v2f bb;
        bb.x = (h0     < HH) ? b1[h0]     : 0.f;
        bb.y = (h0 + 1 < HH) ? b1[h0 + 1] : 0.f;
        c1[i] = acc[i] + bb;
    }
    // bias neuron: pad slot h=55 (k=3, pair 6, .y) fires every step (m: 2 -> 10, >1),
    // its W2 column is b2 -> cur2 arrives with bias already included (all 5 classes).
    if (k == 3) c1[6].y = 2.0f;

    // W2 fragments (70 VGPRs)
    v2f w2r[NC][NP];
#pragma unroll
    for (int c = 0; c < NC; ++c)
#pragma unroll
        for (int i = 0; i < NP; ++i) {
            int h0 = k * HPJ + 2 * i;
            w2r[c][i].x = (h0     < HH) ? W2[c * HH + h0]     : 0.f;
            w2r[c][i].y = (h0 + 1 < HH) ? W2[c * HH + h0 + 1] : 0.f;
        }
    if (k == 3) {
#pragma unroll
        for (int c = 0; c < NC; ++c) w2r[c][6].y = b2[c];
    }

    // RESIDENCY PIN: rounds 0-2 reported VGPR_Count 72/56/88 < the ~134-reg live set,
    // i.e. the allocator rematerialized w2r/c1 loads INSIDE the t-loop (invariant
    // kernarg loads are legal to sink), paying per-step vmcnt stalls. Empty asm with
    // "+v" makes each value an opaque asm output: it can no longer be recomputed from
    // a load, so it must stay register-resident (budget 256 at waves_per_eu(2,2)).
#pragma unroll
    for (int c = 0; c < NC; ++c) {
        asm volatile("" : "+v"(w2r[c][0]), "+v"(w2r[c][1]), "+v"(w2r[c][2]),
                          "+v"(w2r[c][3]), "+v"(w2r[c][4]), "+v"(w2r[c][5]),
                          "+v"(w2r[c][6]));
    }
    asm volatile("" : "+v"(c1[0]), "+v"(c1[1]), "+v"(c1[2]), "+v"(c1[3]),
                      "+v"(c1[4]), "+v"(c1[5]), "+v"(c1[6]));

    // ---------------- Phase 2: 100-step LIF recurrence (software-pipelined) -----
    v2f m1[NP], s1[NP];
#pragma unroll
    for (int i = 0; i < NP; ++i) { m1[i] = (v2f){0.f, 0.f}; s1[i] = (v2f){0.f, 0.f}; }
    float mA = 0.f, sA = 0.f, mB = 0.f, sB = 0.f;

    const size_t stride = (size_t)Brows * NC;
    float* spkBase = out;                          // + t*stride each step (wave-uniform)
    float* memBase = out + (size_t)NS * stride;
    const int offA = row * NC + k;                 // lanes k=0..3 -> 4 consecutive dwords
    const int offB = row * NC + 4;
    const v2f BETA2 = {BETA, BETA};

    v2f cp[NC];
    // layer-1 step: advance m1/s1 one step and produce fresh class partials cp
    auto S1 = [&]() {
#pragma unroll
        for (int c = 0; c < NC; ++c) cp[c] = (v2f){0.f, 0.f};
#pragma unroll
        for (int i = 0; i < NP; ++i) {
            v2f m = __builtin_elementwise_fma(BETA2, m1[i], c1[i]) - s1[i];
            m1[i] = m;
            v2f s = spike2(m);
            s1[i] = s;
#pragma unroll
            for (int c = 0; c < NC; ++c)
                cp[c] = __builtin_elementwise_fma(s, w2r[c][i], cp[c]);
        }
    };

    S1();   // cp for t = 0
#pragma unroll 2
    for (int t = 0; t < NS; ++t) {
        // quad butterfly reduction of step t's partials
        float cur2[NC];
#pragma unroll
        for (int c = 0; c < NC; ++c) {
            float r = cp[c].x + cp[c].y;
            r += dpp_xor1(r);
            r += dpp_xor2(r);
            cur2[c] = r;
        }
        // layer-1 of step t+1 — independent of cur2; scheduler interleaves these
        // ~140 ops into the DPP wait-states and the serial layer-2 chain below.
        // (extra run at t = NS-1 touches no memory; harmless)
        S1();

        float cA = (k == 1) ? cur2[1] : (k == 2) ? cur2[2] :
                   (k == 3) ? cur2[3] : cur2[0];
        float cB = cur2[4];

        mA = fmaf(BETA, mA, cA) - sA;   // b2 folded in via bias neuron
        sA = spike1(mA);
        mB = fmaf(BETA, mB, cB) - sB;
        sB = spike1(mB);

        spkBase[offA] = sA;                   // 4 consecutive dwords per quad
        memBase[offA] = mA;
        if (k == 0) { spkBase[offB] = sB; memBase[offB] = mB; }

        spkBase += stride;
        memBase += stride;
    }
}

extern "C" void kernel_launch(void* const* d_in, const int* in_sizes, int n_in,
                              void* d_out, int out_size, void* d_ws, size_t ws_size,
                              hipStream_t stream) {
    const float* x  = (const float*)d_in[0];
    const float* W1 = (const float*)d_in[1];
    const float* b1 = (const float*)d_in[2];
    const float* W2 = (const float*)d_in[3];
    const float* b2 = (const float*)d_in[4];
    const int*   ns = (const int*)d_in[5];
    int B = in_sizes[0] / DD;          // 32768
    int nblocks = B / RPB;             // 512 -> 2 blocks/CU, 8 waves/CU
    snn_kernel<<<nblocks, BLK, 0, stream>>>(x, W1, b1, W2, b2, ns, (float*)d_out, B);
}